// Round 17
// baseline (205.232 us; speedup 1.0000x reference)
//
#include <hip/hip_runtime.h>
#include <math.h>

#define TGT 32400
#define KLEN 16896
#define EMBED 256
#define HID 512
#define HEADS 8
#define LN_EPS 1e-5f

#define NQT 1013              // ceil(32400/32) layer tiles for Q
#define NKT 528               // 16896/32
#define HROWS ((NQT + NKT) * 32)

typedef __attribute__((ext_vector_type(8))) short bf16x8;
typedef __attribute__((ext_vector_type(4))) short bf16x4;
typedef __attribute__((ext_vector_type(4))) float f32x4;
typedef __attribute__((ext_vector_type(2))) __bf16 bfv2;

__device__ inline short f2bf(float f) {
    union { float f; unsigned u; } v; v.f = f;
    unsigned r = v.u + 0x7FFF + ((v.u >> 16) & 1);
    return (short)(r >> 16);
}
__device__ inline float bf2f(short s) {
    union { unsigned u; float f; } v;
    v.u = ((unsigned)(unsigned short)s) << 16;
    return v.f;
}
__device__ inline void gload_lds16(const short* g, short* l) {
    __builtin_amdgcn_global_load_lds(
        (const __attribute__((address_space(1))) void*)g,
        (__attribute__((address_space(3))) void*)l,
        16, 0, 0);
}

// 8-elem bf16 dot with f32 accumulate; hw dot2 when available
__device__ inline float dot8(bf16x8 q, bf16x8 k, float s) {
#if __has_builtin(__builtin_amdgcn_fdot2_f32_bf16)
    union { bf16x8 v; bfv2 p[4]; } qu, ku;
    qu.v = q; ku.v = k;
#pragma unroll
    for (int p = 0; p < 4; ++p)
        s = __builtin_amdgcn_fdot2_f32_bf16(qu.p[p], ku.p[p], s, false);
#else
#pragma unroll
    for (int e = 0; e < 8; ++e) s += bf2f(q[e]) * bf2f(k[e]);
#endif
    return s;
}

// ---------------- wave helpers (wave64) ----------------
__device__ inline float wave_sum(float v) {
#pragma unroll
    for (int o = 32; o; o >>= 1) v += __shfl_xor(v, o);
    return v;
}
__device__ inline int wave_incl_scan(int v) {
    int lane = threadIdx.x & 63;
#pragma unroll
    for (int o = 1; o < 64; o <<= 1) {
        int x = __shfl_up(v, o);
        if (lane >= o) v += x;
    }
    return v;
}

// ---------------- prep: value->v8 (head-major bf16), weight transpose, histogram ----------------
__global__ __launch_bounds__(256) void prep_kernel(
    const float* __restrict__ value, short* __restrict__ v8,
    const float* __restrict__ wq1, const float* __restrict__ wq2,
    const float* __restrict__ wk1, const float* __restrict__ wk2,
    short* __restrict__ Wt,
    const int* __restrict__ rbev, int N, int* __restrict__ count)
{
    int bid = blockIdx.x;
    if (bid < 2112) {
        int idx = bid * 256 + threadIdx.x;       // chunk of 8 floats
        int f = idx >> 5;                        // row
        int ch = idx & 31;                       // chunk in row
        const float4* s4 = (const float4*)(value + (size_t)f * 256 + ch * 8);
        float4 a = s4[0], b = s4[1];
        bf16x8 pk;
        pk[0] = f2bf(a.x); pk[1] = f2bf(a.y); pk[2] = f2bf(a.z); pk[3] = f2bf(a.w);
        pk[4] = f2bf(b.x); pk[5] = f2bf(b.y); pk[6] = f2bf(b.z); pk[7] = f2bf(b.w);
        int head = ch >> 2;
        int within = (ch & 3) * 8;
        *(bf16x8*)(v8 + ((size_t)head * KLEN + f) * 32 + within) = pk;
    } else if (bid < 4160) {
        int i = (bid - 2112) * 256 + threadIdx.x;
        int m = i >> 17;
        int r17 = i & 131071;
        int logC = (m & 1) ? 8 : 9;
        int C = 1 << logC;
        int c = r17 & (C - 1);
        int r = r17 >> logC;
        int R = 131072 >> logC;
        const float* W = (m == 0) ? wq1 : (m == 1) ? wq2 : (m == 2) ? wk1 : wk2;
        Wt[(size_t)m * 131072 + (size_t)c * R + r] = f2bf(W[r17]);
    } else {
        int n = (bid - 4160) * 256 + threadIdx.x;
        if (n < N) atomicAdd(&count[rbev[n]], 1);
    }
}

// ---------------- MLP layer 1: persistent, W1-in-registers ----------------
#define XPAD 264
__global__ __launch_bounds__(512, 2) void mlpA_kernel(
    const float* __restrict__ Xq, const float* __restrict__ Xk,
    const short* __restrict__ Wt,
    const float* __restrict__ bq1, const float* __restrict__ bk1,
    short* __restrict__ Hg, int nQblocks)
{
    __shared__ short sX[2][32 * XPAD];

    const int t = threadIdx.x;
    const int wid = t >> 6, lane = t & 63;
    const int lrow = lane & 15, kch = lane >> 4;

    const bool isQ = (int)blockIdx.x < nQblocks;
    const int bid = isQ ? blockIdx.x : blockIdx.x - nQblocks;
    const int stride = isQ ? nQblocks : (gridDim.x - nQblocks);
    const int nT = isQ ? NQT : NKT;
    const int M = isQ ? TGT : KLEN;
    const float* X = isQ ? Xq : Xk;
    const short* W1t = Wt + (size_t)(isQ ? 0 : 2) * 131072;
    const float* b1 = isQ ? bq1 : bk1;
    const int hbase = isQ ? 0 : NQT * 32;

    const int colBase = 64 * wid + lrow;

    bf16x8 w1r[8][4];
#pragma unroll
    for (int ks = 0; ks < 8; ++ks)
#pragma unroll
        for (int j = 0; j < 4; ++j)
            w1r[ks][j] = *(const bf16x8*)(W1t + (size_t)(colBase + 16 * j) * 256 + 32 * ks + 8 * kch);
    float4 bb[4];
#pragma unroll
    for (int j = 0; j < 4; ++j)
        bb[j] = *(const float4*)(b1 + 64 * wid + 16 * j + 4 * kch);

    const int srow = t >> 4, sp = t & 15;

    float4 r0[4], r1[4];
    int tile = bid;
    if (tile < nT) {
        int gr = tile * 32 + srow; if (gr > M - 1) gr = M - 1;
        const float* base = X + (size_t)gr * 256;
#pragma unroll
        for (int i = 0; i < 4; ++i) r0[i] = *(const float4*)(base + (sp + 16 * i) * 4);
    }
    int sel = 0;

    for (; tile < nT; tile += stride) {
#pragma unroll
        for (int i = 0; i < 4; ++i) {
            int c = sp + 16 * i;
            bf16x4 pk;
            pk[0] = f2bf(r0[i].x); pk[1] = f2bf(r0[i].y);
            pk[2] = f2bf(r0[i].z); pk[3] = f2bf(r0[i].w);
            *(bf16x4*)&sX[sel][srow * XPAD + c * 4] = pk;
        }
        int nx = tile + stride;
        if (nx < nT) {
            int gr = nx * 32 + srow; if (gr > M - 1) gr = M - 1;
            const float* base = X + (size_t)gr * 256;
#pragma unroll
            for (int i = 0; i < 4; ++i) r1[i] = *(const float4*)(base + (sp + 16 * i) * 4);
        }
        asm volatile("s_waitcnt lgkmcnt(0)" ::: "memory");
        __builtin_amdgcn_sched_barrier(0);
        __builtin_amdgcn_s_barrier();
        asm volatile("" ::: "memory");

        f32x4 acc[2][4];
#pragma unroll
        for (int rt = 0; rt < 2; ++rt)
#pragma unroll
            for (int j = 0; j < 4; ++j) acc[rt][j] = (f32x4){0.f, 0.f, 0.f, 0.f};

        const short* xs = sX[sel];
#pragma unroll
        for (int ks = 0; ks < 8; ++ks) {
            bf16x8 af[2];
#pragma unroll
            for (int rt = 0; rt < 2; ++rt)
                af[rt] = *(const bf16x8*)&xs[(16 * rt + lrow) * XPAD + 32 * ks + 8 * kch];
#pragma unroll
            for (int j = 0; j < 4; ++j)
#pragma unroll
                for (int rt = 0; rt < 2; ++rt)
                    acc[rt][j] = __builtin_amdgcn_mfma_f32_16x16x32_bf16(w1r[ks][j], af[rt], acc[rt][j], 0, 0, 0);
        }

        int hr0 = hbase + tile * 32;
#pragma unroll
        for (int j = 0; j < 4; ++j) {
#pragma unroll
            for (int rt = 0; rt < 2; ++rt) {
                bf16x4 pk;
                pk[0] = f2bf(fmaxf(acc[rt][j][0] + bb[j].x, 0.f));
                pk[1] = f2bf(fmaxf(acc[rt][j][1] + bb[j].y, 0.f));
                pk[2] = f2bf(fmaxf(acc[rt][j][2] + bb[j].z, 0.f));
                pk[3] = f2bf(fmaxf(acc[rt][j][3] + bb[j].w, 0.f));
                *(bf16x4*)(Hg + (size_t)(hr0 + 16 * rt + lrow) * 512 + 64 * wid + 16 * j + 4 * kch) = pk;
            }
        }
#pragma unroll
        for (int i = 0; i < 4; ++i) r0[i] = r1[i];
        sel ^= 1;
    }
}

// ---------------- MLP layer 2: persistent, W2-in-registers, writes head-major q8/k8 ----------------
__global__ __launch_bounds__(512, 2) void mlpB_kernel(
    const short* __restrict__ Hg, const short* __restrict__ Wt,
    const float* __restrict__ bq2, const float* __restrict__ bk2,
    short* __restrict__ q8, short* __restrict__ k8,
    float scaleQ, int nQblocks)
{
    __shared__ short sX[2][32 * 512];

    const int t = threadIdx.x;
    const int wid = t >> 6, lane = t & 63;
    const int lrow = lane & 15, kch = lane >> 4;

    const bool isQ = (int)blockIdx.x < nQblocks;
    const int bid = isQ ? blockIdx.x : blockIdx.x - nQblocks;
    const int stride = isQ ? nQblocks : (gridDim.x - nQblocks);
    const int nT = isQ ? NQT : NKT;
    const int M = isQ ? TGT : KLEN;
    const short* W2t = Wt + (size_t)(isQ ? 1 : 3) * 131072;
    const float* b2 = isQ ? bq2 : bk2;
    short* Y8 = isQ ? q8 : k8;
    const int hbase = isQ ? 0 : NQT * 32;
    const float scale = isQ ? scaleQ : 1.0f;

    const int colBase = 32 * wid + lrow;

    bf16x8 w2r[16][2];
#pragma unroll
    for (int ks = 0; ks < 16; ++ks)
#pragma unroll
        for (int ct = 0; ct < 2; ++ct)
            w2r[ks][ct] = *(const bf16x8*)(W2t + (size_t)(colBase + 16 * ct) * 512 + 32 * ks + 8 * kch);
    float4 bb[2];
#pragma unroll
    for (int ct = 0; ct < 2; ++ct)
        bb[ct] = *(const float4*)(b2 + 32 * wid + 16 * ct + 4 * kch);

    auto stage = [&](int tt, int s) {
#pragma unroll
        for (int i = 0; i < 4; ++i) {
            int baseslot = i * 512 + wid * 64;
            int slot = baseslot + lane;
            int r = slot >> 6;
            int d = slot & 63;
            int cs = d ^ (r & 7);
            gload_lds16(Hg + (size_t)(hbase + tt * 32 + r) * 512 + cs * 8,
                        &sX[s][baseslot * 8]);
        }
    };

    int tile = bid;
    int sel = 0;
    if (tile < nT) stage(tile, 0);

    for (; tile < nT; tile += stride) {
        asm volatile("s_waitcnt vmcnt(0)" ::: "memory");
        __builtin_amdgcn_sched_barrier(0);
        __builtin_amdgcn_s_barrier();
        asm volatile("" ::: "memory");
        int nx = tile + stride;
        if (nx < nT) stage(nx, sel ^ 1);
        __builtin_amdgcn_sched_barrier(0);

        f32x4 acc[2][2];
#pragma unroll
        for (int ct = 0; ct < 2; ++ct)
#pragma unroll
            for (int rt = 0; rt < 2; ++rt) acc[ct][rt] = (f32x4){0.f, 0.f, 0.f, 0.f};

        const short* xs = sX[sel];
#pragma unroll
        for (int ks = 0; ks < 16; ++ks) {
            bf16x8 hf[2];
#pragma unroll
            for (int rt = 0; rt < 2; ++rt) {
                int row = 16 * rt + lrow;
                hf[rt] = *(const bf16x8*)&xs[row * 512 + (((4 * ks + kch) ^ (row & 7)) << 3)];
            }
#pragma unroll
            for (int ct = 0; ct < 2; ++ct)
#pragma unroll
                for (int rt = 0; rt < 2; ++rt)
                    acc[ct][rt] = __builtin_amdgcn_mfma_f32_16x16x32_bf16(w2r[ks][ct], hf[rt], acc[ct][rt], 0, 0, 0);
        }

        int gr0 = tile * 32;
#pragma unroll
        for (int ct = 0; ct < 2; ++ct) {
#pragma unroll
            for (int rt = 0; rt < 2; ++rt) {
                int gr = gr0 + 16 * rt + lrow;
                if (gr < M) {
                    bf16x4 pk;
                    pk[0] = f2bf((acc[ct][rt][0] + bb[ct].x) * scale);
                    pk[1] = f2bf((acc[ct][rt][1] + bb[ct].y) * scale);
                    pk[2] = f2bf((acc[ct][rt][2] + bb[ct].z) * scale);
                    pk[3] = f2bf((acc[ct][rt][3] + bb[ct].w) * scale);
                    *(bf16x4*)(Y8 + ((size_t)wid * M + gr) * 32 + 16 * ct + 4 * kch) = pk;
                }
            }
        }
        sel ^= 1;
    }
}

// ---------------- logits + softmax: 4-lane group per (f,js); dot2 + len-skip ----------------
__global__ __launch_bounds__(256, 2) void logits8_kernel(
    const short* __restrict__ q8, const short* __restrict__ k8,
    const int* __restrict__ rbev, const int* __restrict__ starts,
    const int* __restrict__ lengths, int rn,
    float* __restrict__ Wsm, short* __restrict__ Wg8)
{
    const int h = blockIdx.x & 7;
    const int fb = blockIdx.x >> 3;
    const int t = threadIdx.x;
    const int w = t >> 6;
    const int lane = t & 63;
    const int fsub = lane >> 5;       // 0..1
    const int js = (lane >> 2) & 7;   // 0..7
    const int c = lane & 3;           // chunk 0..3
    const int f = fb * 8 + w * 2 + fsub;
    const int st = starts[f], len = lengths[f];
    const int ntt = (len + 7) >> 3;   // live slots (wave-uniform per feature half)

    // k chunk c — raw bf16, no conversion needed for dot2
    bf16x8 kv = *(const bf16x8*)(k8 + ((size_t)h * KLEN + f) * 32 + c * 8);
    const short* qbase = q8 + (size_t)h * TGT * 32;

    // preload indices, then q-chunks back-to-back (ILP)
    int bidx[5];
#pragma unroll
    for (int tt = 0; tt < 5; ++tt) {
        int j = js + 8 * tt;
        bidx[tt] = (j < len) ? rbev[st + j] : 0;
    }
    bf16x8 qv[5];
#pragma unroll
    for (int tt = 0; tt < 5; ++tt)
        qv[tt] = *(const bf16x8*)(qbase + (size_t)bidx[tt] * 32 + c * 8);

    float lg[5];
#pragma unroll
    for (int tt = 0; tt < 5; ++tt) {
        if (tt < ntt) {
            float s = dot8(qv[tt], kv, 0.f);
            s += __shfl_xor(s, 1);
            s += __shfl_xor(s, 2);
            lg[tt] = (js + 8 * tt < len) ? s : -3.0e38f;
        } else {
            lg[tt] = -3.0e38f;
        }
    }

    // softmax over j: reduce across js (stride 4)
    float m = fmaxf(fmaxf(fmaxf(lg[0], lg[1]), fmaxf(lg[2], lg[3])), lg[4]);
    m = fmaxf(m, __shfl_xor(m, 4));
    m = fmaxf(m, __shfl_xor(m, 8));
    m = fmaxf(m, __shfl_xor(m, 16));
    float ex[5];
    float sum = 0.f;
#pragma unroll
    for (int tt = 0; tt < 5; ++tt) {
        int j = js + 8 * tt;
        float e = (j < len) ? __expf(lg[tt] - m) : 0.f;
        ex[tt] = e;
        sum += e;
    }
    sum += __shfl_xor(sum, 4);
    sum += __shfl_xor(sum, 8);
    sum += __shfl_xor(sum, 16);
    float inv = 1.f / sum;

    if (c == 0) {
        float* wrow = Wsm + ((size_t)f * HEADS + h) * rn;
        short* grow = Wg8 + ((size_t)h * KLEN + f) * rn;
#pragma unroll
        for (int tt = 0; tt < 5; ++tt) {
            int j = js + 8 * tt;
            if (j < rn) {
                float wv = (j < len) ? ex[tt] * inv : 0.f;
                wrow[j] = wv;
                if (j < len) grow[j] = f2bf(wv);
            }
        }
    }
}

// ---------------- block-scan: coalesced int4 loads, 8 elems/thread, 4 chunks ----------------
__global__ __launch_bounds__(1024) void scan_kernel(
    const int* __restrict__ count, int n,
    int* __restrict__ offs, int* __restrict__ cursor)
{
    __shared__ int wsum[16];
    __shared__ int carry_s;
    const int t = threadIdx.x;
    const int lane = t & 63, wid = t >> 6;
    if (t == 0) carry_s = 0;
    __syncthreads();

    for (int base = 0; base < n; base += 8192) {
        int idx0 = base + t * 8;
        int v[8];
        if (idx0 + 8 <= n) {
            int4 a = *(const int4*)(count + idx0);
            int4 b = *(const int4*)(count + idx0 + 4);
            v[0] = a.x; v[1] = a.y; v[2] = a.z; v[3] = a.w;
            v[4] = b.x; v[5] = b.y; v[6] = b.z; v[7] = b.w;
        } else {
#pragma unroll
            for (int i = 0; i < 8; ++i) v[i] = (idx0 + i < n) ? count[idx0 + i] : 0;
        }
        int loc[8];
        int s = 0;
#pragma unroll
        for (int i = 0; i < 8; ++i) { loc[i] = s; s += v[i]; }
        int incl = wave_incl_scan(s);
        if (lane == 63) wsum[wid] = incl;
        __syncthreads();
        if (wid == 0) {
            int x = (lane < 16) ? wsum[lane] : 0;
            int xi = wave_incl_scan(x);
            if (lane < 16) wsum[lane] = xi;
        }
        __syncthreads();
        int waveoff = (wid > 0) ? wsum[wid - 1] : 0;
        int carry = carry_s;
        int excl = carry + waveoff + incl - s;
        int o[8];
#pragma unroll
        for (int i = 0; i < 8; ++i) o[i] = excl + loc[i];
        if (idx0 + 8 <= n) {
            *(int4*)(offs + idx0)     = make_int4(o[0], o[1], o[2], o[3]);
            *(int4*)(offs + idx0 + 4) = make_int4(o[4], o[5], o[6], o[7]);
            *(int4*)(cursor + idx0)     = make_int4(o[0], o[1], o[2], o[3]);
            *(int4*)(cursor + idx0 + 4) = make_int4(o[4], o[5], o[6], o[7]);
        } else {
#pragma unroll
            for (int i = 0; i < 8; ++i)
                if (idx0 + i < n) { offs[idx0 + i] = o[i]; cursor[idx0 + i] = o[i]; }
        }
        __syncthreads();
        if (t == 1023) carry_s = carry + waveoff + incl;
        __syncthreads();
    }
    if (t == 0) offs[n] = carry_s;
}

// ---------------- permutation fill: pack (f,j) ----------------
__global__ __launch_bounds__(256) void perm_kernel(
    const int* __restrict__ rbev, const int* __restrict__ rfeat,
    const int* __restrict__ starts, int N,
    int* __restrict__ cursor, int* __restrict__ perm)
{
    int n = blockIdx.x * 256 + threadIdx.x;
    if (n < N) {
        int b = rbev[n];
        int f = rfeat[n];
        int j = n - starts[f];
        int pos = atomicAdd(&cursor[b], 1);
        perm[pos] = (f << 6) | j;
    }
}

// ---------------- gather, head-split: 4-thread group per (row,h), explicit ILP ----------------
__global__ __launch_bounds__(256, 2) void gather8_kernel(
    const short* __restrict__ v8, const short* __restrict__ Wg8,
    const int* __restrict__ perm, const int* __restrict__ offs, int rn,
    float* __restrict__ out)
{
    const int h = blockIdx.x & 7;
    const int rb = blockIdx.x >> 3;
    const int t = threadIdx.x;
    const int r = rb * 64 + (t >> 2);
    if (r >= TGT) return;
    const int c = t & 3;
    const int lane = t & 63;
    const int gl = lane & ~3;           // group's base lane
    const short* vbase = v8 + (size_t)h * KLEN * 32 + c * 8;
    const short* wbase = Wg8 + (size_t)h * KLEN * rn;
    const int beg = offs[r], end = offs[r + 1];
    const int cnt = end - beg;
    float acc[8];
#pragma unroll
    for (int e = 0; e < 8; ++e) acc[e] = 0.f;

    for (int base = 0; base < cnt; base += 8) {
        int pk0 = (base + c < cnt) ? perm[beg + base + c] : 0;
        int pk1 = (base + 4 + c < cnt) ? perm[beg + base + 4 + c] : 0;
        short ws[8];
        bf16x8 vv[8];
#pragma unroll
        for (int u = 0; u < 8; ++u) {
            int pku = __shfl(u < 4 ? pk0 : pk1, gl + (u & 3));
            int fo = pku >> 6, j = pku & 63;
            ws[u] = wbase[(size_t)fo * rn + j];
            vv[u] = *(const bf16x8*)(vbase + (size_t)fo * 32);
        }
#pragma unroll
        for (int u = 0; u < 8; ++u) {
            float w = (base + u < cnt) ? bf2f(ws[u]) : 0.f;
#pragma unroll
            for (int e = 0; e < 8; ++e) acc[e] += w * bf2f(vv[u][e]);
        }
    }
    float* o = out + (size_t)r * EMBED + h * 32 + c * 8;
    *(float4*)(o)     = make_float4(acc[0], acc[1], acc[2], acc[3]);
    *(float4*)(o + 4) = make_float4(acc[4], acc[5], acc[6], acc[7]);
}

// ---------------- layernorm in place: one wave per row ----------------
__global__ __launch_bounds__(256) void ln_kernel(
    float* __restrict__ out, const float* __restrict__ g, const float* __restrict__ b)
{
    int row = blockIdx.x * 4 + (threadIdx.x >> 6);
    if (row >= TGT) return;
    int lane = threadIdx.x & 63;
    float4 x = *(float4*)(out + (size_t)row * EMBED + lane * 4);
    float mu = wave_sum(x.x + x.y + x.z + x.w) * (1.f / EMBED);
    float dx = x.x - mu, dy = x.y - mu, dz = x.z - mu, dw = x.w - mu;
    float var = wave_sum(dx * dx + dy * dy + dz * dz + dw * dw) * (1.f / EMBED);
    float rs = rsqrtf(var + LN_EPS);
    float4 gg = *(const float4*)(g + lane * 4);
    float4 bb = *(const float4*)(b + lane * 4);
    float4 y;
    y.x = dx * rs * gg.x + bb.x;
    y.y = dy * rs * gg.y + bb.y;
    y.z = dz * rs * gg.z + bb.z;
    y.w = dw * rs * gg.w + bb.w;
    *(float4*)(out + (size_t)row * EMBED + lane * 4) = y;
}

extern "C" void kernel_launch(void* const* d_in, const int* in_sizes, int n_in,
                              void* d_out, int out_size, void* d_ws, size_t ws_size,
                              hipStream_t stream) {
    const float* query  = (const float*)d_in[0];
    const float* key_in = (const float*)d_in[1];
    const float* value  = (const float*)d_in[2];
    const int* rfeat    = (const int*)d_in[3];
    const int* rbev     = (const int*)d_in[4];
    const int* starts   = (const int*)d_in[5];
    const int* lengths  = (const int*)d_in[6];
    const float* wq1 = (const float*)d_in[7];
    const float* bq1 = (const float*)d_in[8];
    const float* wq2 = (const float*)d_in[9];
    const float* bq2 = (const float*)d_in[10];
    const float* wk1 = (const float*)d_in[11];
    const float* bk1 = (const float*)d_in[12];
    const float* wk2 = (const float*)d_in[13];
    const float* bk2 = (const float*)d_in[14];
    const float* ln_g = (const float*)d_in[15];
    const float* ln_b = (const float*)d_in[16];

    const int N = in_sizes[3];
    const int rn = (out_size - TGT * EMBED) / (KLEN * HEADS); // ref_num

    float* outp = (float*)d_out;
    float* Wsm  = outp + (size_t)TGT * EMBED;

    // workspace layout
    short* Hg   = (short*)d_ws;                          // HROWS*512 bf16
    short* q8   = Hg + (size_t)HROWS * 512;              // 8*TGT*32 bf16
    short* k8   = q8 + (size_t)TGT * EMBED;              // 8*KLEN*32 bf16
    short* v8   = k8 + (size_t)KLEN * EMBED;             // 8*KLEN*32 bf16
    short* Wt   = v8 + (size_t)KLEN * EMBED;             // 4*131072 bf16
    short* Wg8  = Wt + 4 * 131072;                       // 8*KLEN*rn bf16
    int* count  = (int*)(Wg8 + (size_t)HEADS * KLEN * rn);
    int* offs   = count + TGT;                           // TGT+1
    int* cursor = offs + TGT + 1;                        // TGT
    int* perm   = cursor + TGT;                          // N

    const float scaling = 0.1767766952966369f; // 32^-0.5
    const int nQblocks = 168;

    hipMemsetAsync(count, 0, TGT * sizeof(int), stream);

    int hist_blocks = (N + 255) / 256;
    prep_kernel<<<4160 + hist_blocks, 256, 0, stream>>>(
        value, v8, wq1, wq2, wk1, wk2, Wt, rbev, N, count);

    mlpA_kernel<<<256, 512, 0, stream>>>(query, key_in, Wt, bq1, bk1, Hg, nQblocks);
    mlpB_kernel<<<256, 512, 0, stream>>>(Hg, Wt, bq2, bk2, q8, k8, scaling, nQblocks);

    scan_kernel<<<1, 1024, 0, stream>>>(count, TGT, offs, cursor);
    perm_kernel<<<(N + 255) / 256, 256, 0, stream>>>(rbev, rfeat, starts, N, cursor, perm);

    logits8_kernel<<<8 * (KLEN / 8), 256, 0, stream>>>(
        q8, k8, rbev, starts, lengths, rn, Wsm, Wg8);

    gather8_kernel<<<8 * ((TGT + 63) / 64), 256, 0, stream>>>(
        v8, Wg8, perm, offs, rn, outp);
    ln_kernel<<<(TGT + 3) / 4, 256, 0, stream>>>(outp, ln_g, ln_b);
}

// Round 18
// 204.158 us; speedup vs baseline: 1.0053x; 1.0053x over previous
//
#include <hip/hip_runtime.h>
#include <math.h>

#define TGT 32400
#define KLEN 16896
#define EMBED 256
#define HID 512
#define HEADS 8
#define LN_EPS 1e-5f

#define NQT 1013              // ceil(32400/32) layer tiles for Q
#define NKT 528               // 16896/32
#define HROWS ((NQT + NKT) * 32)

typedef __attribute__((ext_vector_type(8))) short bf16x8;
typedef __attribute__((ext_vector_type(4))) short bf16x4;
typedef __attribute__((ext_vector_type(4))) float f32x4;
typedef __attribute__((ext_vector_type(2))) __bf16 bfv2;

__device__ inline short f2bf(float f) {
    union { float f; unsigned u; } v; v.f = f;
    unsigned r = v.u + 0x7FFF + ((v.u >> 16) & 1);
    return (short)(r >> 16);
}
__device__ inline float bf2f(short s) {
    union { unsigned u; float f; } v;
    v.u = ((unsigned)(unsigned short)s) << 16;
    return v.f;
}
__device__ inline void gload_lds16(const short* g, short* l) {
    __builtin_amdgcn_global_load_lds(
        (const __attribute__((address_space(1))) void*)g,
        (__attribute__((address_space(3))) void*)l,
        16, 0, 0);
}

// 8-elem bf16 dot with f32 accumulate; hw dot2 when available
__device__ inline float dot8(bf16x8 q, bf16x8 k, float s) {
#if __has_builtin(__builtin_amdgcn_fdot2_f32_bf16)
    union { bf16x8 v; bfv2 p[4]; } qu, ku;
    qu.v = q; ku.v = k;
#pragma unroll
    for (int p = 0; p < 4; ++p)
        s = __builtin_amdgcn_fdot2_f32_bf16(qu.p[p], ku.p[p], s, false);
#else
#pragma unroll
    for (int e = 0; e < 8; ++e) s += bf2f(q[e]) * bf2f(k[e]);
#endif
    return s;
}

// ---------------- wave helpers (wave64) ----------------
__device__ inline float wave_sum(float v) {
#pragma unroll
    for (int o = 32; o; o >>= 1) v += __shfl_xor(v, o);
    return v;
}
__device__ inline int wave_incl_scan(int v) {
    int lane = threadIdx.x & 63;
#pragma unroll
    for (int o = 1; o < 64; o <<= 1) {
        int x = __shfl_up(v, o);
        if (lane >= o) v += x;
    }
    return v;
}

// ---------------- prep: value->v8 (head-major bf16), weight transpose, histogram ----------------
__global__ __launch_bounds__(256) void prep_kernel(
    const float* __restrict__ value, short* __restrict__ v8,
    const float* __restrict__ wq1, const float* __restrict__ wq2,
    const float* __restrict__ wk1, const float* __restrict__ wk2,
    short* __restrict__ Wt,
    const int* __restrict__ rbev, int N, int* __restrict__ count)
{
    int bid = blockIdx.x;
    if (bid < 2112) {
        int idx = bid * 256 + threadIdx.x;       // chunk of 8 floats
        int f = idx >> 5;                        // row
        int ch = idx & 31;                       // chunk in row
        const float4* s4 = (const float4*)(value + (size_t)f * 256 + ch * 8);
        float4 a = s4[0], b = s4[1];
        bf16x8 pk;
        pk[0] = f2bf(a.x); pk[1] = f2bf(a.y); pk[2] = f2bf(a.z); pk[3] = f2bf(a.w);
        pk[4] = f2bf(b.x); pk[5] = f2bf(b.y); pk[6] = f2bf(b.z); pk[7] = f2bf(b.w);
        int head = ch >> 2;
        int within = (ch & 3) * 8;
        *(bf16x8*)(v8 + ((size_t)head * KLEN + f) * 32 + within) = pk;
    } else if (bid < 4160) {
        int i = (bid - 2112) * 256 + threadIdx.x;
        int m = i >> 17;
        int r17 = i & 131071;
        int logC = (m & 1) ? 8 : 9;
        int C = 1 << logC;
        int c = r17 & (C - 1);
        int r = r17 >> logC;
        int R = 131072 >> logC;
        const float* W = (m == 0) ? wq1 : (m == 1) ? wq2 : (m == 2) ? wk1 : wk2;
        Wt[(size_t)m * 131072 + (size_t)c * R + r] = f2bf(W[r17]);
    } else {
        int n = (bid - 4160) * 256 + threadIdx.x;
        if (n < N) atomicAdd(&count[rbev[n]], 1);
    }
}

// ---------------- MLP layer 1: persistent, W1-in-registers ----------------
#define XPAD 264
__global__ __launch_bounds__(512, 2) void mlpA_kernel(
    const float* __restrict__ Xq, const float* __restrict__ Xk,
    const short* __restrict__ Wt,
    const float* __restrict__ bq1, const float* __restrict__ bk1,
    short* __restrict__ Hg, int nQblocks)
{
    __shared__ short sX[2][32 * XPAD];

    const int t = threadIdx.x;
    const int wid = t >> 6, lane = t & 63;
    const int lrow = lane & 15, kch = lane >> 4;

    const bool isQ = (int)blockIdx.x < nQblocks;
    const int bid = isQ ? blockIdx.x : blockIdx.x - nQblocks;
    const int stride = isQ ? nQblocks : (gridDim.x - nQblocks);
    const int nT = isQ ? NQT : NKT;
    const int M = isQ ? TGT : KLEN;
    const float* X = isQ ? Xq : Xk;
    const short* W1t = Wt + (size_t)(isQ ? 0 : 2) * 131072;
    const float* b1 = isQ ? bq1 : bk1;
    const int hbase = isQ ? 0 : NQT * 32;

    const int colBase = 64 * wid + lrow;

    bf16x8 w1r[8][4];
#pragma unroll
    for (int ks = 0; ks < 8; ++ks)
#pragma unroll
        for (int j = 0; j < 4; ++j)
            w1r[ks][j] = *(const bf16x8*)(W1t + (size_t)(colBase + 16 * j) * 256 + 32 * ks + 8 * kch);
    float4 bb[4];
#pragma unroll
    for (int j = 0; j < 4; ++j)
        bb[j] = *(const float4*)(b1 + 64 * wid + 16 * j + 4 * kch);

    const int srow = t >> 4, sp = t & 15;

    float4 r0[4], r1[4];
    int tile = bid;
    if (tile < nT) {
        int gr = tile * 32 + srow; if (gr > M - 1) gr = M - 1;
        const float* base = X + (size_t)gr * 256;
#pragma unroll
        for (int i = 0; i < 4; ++i) r0[i] = *(const float4*)(base + (sp + 16 * i) * 4);
    }
    int sel = 0;

    for (; tile < nT; tile += stride) {
#pragma unroll
        for (int i = 0; i < 4; ++i) {
            int c = sp + 16 * i;
            bf16x4 pk;
            pk[0] = f2bf(r0[i].x); pk[1] = f2bf(r0[i].y);
            pk[2] = f2bf(r0[i].z); pk[3] = f2bf(r0[i].w);
            *(bf16x4*)&sX[sel][srow * XPAD + c * 4] = pk;
        }
        int nx = tile + stride;
        if (nx < nT) {
            int gr = nx * 32 + srow; if (gr > M - 1) gr = M - 1;
            const float* base = X + (size_t)gr * 256;
#pragma unroll
            for (int i = 0; i < 4; ++i) r1[i] = *(const float4*)(base + (sp + 16 * i) * 4);
        }
        asm volatile("s_waitcnt lgkmcnt(0)" ::: "memory");
        __builtin_amdgcn_sched_barrier(0);
        __builtin_amdgcn_s_barrier();
        asm volatile("" ::: "memory");

        f32x4 acc[2][4];
#pragma unroll
        for (int rt = 0; rt < 2; ++rt)
#pragma unroll
            for (int j = 0; j < 4; ++j) acc[rt][j] = (f32x4){0.f, 0.f, 0.f, 0.f};

        const short* xs = sX[sel];
#pragma unroll
        for (int ks = 0; ks < 8; ++ks) {
            bf16x8 af[2];
#pragma unroll
            for (int rt = 0; rt < 2; ++rt)
                af[rt] = *(const bf16x8*)&xs[(16 * rt + lrow) * XPAD + 32 * ks + 8 * kch];
#pragma unroll
            for (int j = 0; j < 4; ++j)
#pragma unroll
                for (int rt = 0; rt < 2; ++rt)
                    acc[rt][j] = __builtin_amdgcn_mfma_f32_16x16x32_bf16(w1r[ks][j], af[rt], acc[rt][j], 0, 0, 0);
        }

        int hr0 = hbase + tile * 32;
#pragma unroll
        for (int j = 0; j < 4; ++j) {
#pragma unroll
            for (int rt = 0; rt < 2; ++rt) {
                bf16x4 pk;
                pk[0] = f2bf(fmaxf(acc[rt][j][0] + bb[j].x, 0.f));
                pk[1] = f2bf(fmaxf(acc[rt][j][1] + bb[j].y, 0.f));
                pk[2] = f2bf(fmaxf(acc[rt][j][2] + bb[j].z, 0.f));
                pk[3] = f2bf(fmaxf(acc[rt][j][3] + bb[j].w, 0.f));
                *(bf16x4*)(Hg + (size_t)(hr0 + 16 * rt + lrow) * 512 + 64 * wid + 16 * j + 4 * kch) = pk;
            }
        }
#pragma unroll
        for (int i = 0; i < 4; ++i) r0[i] = r1[i];
        sel ^= 1;
    }
}

// ---------------- MLP layer 2: persistent, W2-in-registers, writes head-major q8/k8 ----------------
__global__ __launch_bounds__(512, 2) void mlpB_kernel(
    const short* __restrict__ Hg, const short* __restrict__ Wt,
    const float* __restrict__ bq2, const float* __restrict__ bk2,
    short* __restrict__ q8, short* __restrict__ k8,
    float scaleQ, int nQblocks)
{
    __shared__ short sX[2][32 * 512];

    const int t = threadIdx.x;
    const int wid = t >> 6, lane = t & 63;
    const int lrow = lane & 15, kch = lane >> 4;

    const bool isQ = (int)blockIdx.x < nQblocks;
    const int bid = isQ ? blockIdx.x : blockIdx.x - nQblocks;
    const int stride = isQ ? nQblocks : (gridDim.x - nQblocks);
    const int nT = isQ ? NQT : NKT;
    const int M = isQ ? TGT : KLEN;
    const short* W2t = Wt + (size_t)(isQ ? 1 : 3) * 131072;
    const float* b2 = isQ ? bq2 : bk2;
    short* Y8 = isQ ? q8 : k8;
    const int hbase = isQ ? 0 : NQT * 32;
    const float scale = isQ ? scaleQ : 1.0f;

    const int colBase = 32 * wid + lrow;

    bf16x8 w2r[16][2];
#pragma unroll
    for (int ks = 0; ks < 16; ++ks)
#pragma unroll
        for (int ct = 0; ct < 2; ++ct)
            w2r[ks][ct] = *(const bf16x8*)(W2t + (size_t)(colBase + 16 * ct) * 512 + 32 * ks + 8 * kch);
    float4 bb[2];
#pragma unroll
    for (int ct = 0; ct < 2; ++ct)
        bb[ct] = *(const float4*)(b2 + 32 * wid + 16 * ct + 4 * kch);

    auto stage = [&](int tt, int s) {
#pragma unroll
        for (int i = 0; i < 4; ++i) {
            int baseslot = i * 512 + wid * 64;
            int slot = baseslot + lane;
            int r = slot >> 6;
            int d = slot & 63;
            int cs = d ^ (r & 7);
            gload_lds16(Hg + (size_t)(hbase + tt * 32 + r) * 512 + cs * 8,
                        &sX[s][baseslot * 8]);
        }
    };

    int tile = bid;
    int sel = 0;
    if (tile < nT) stage(tile, 0);

    for (; tile < nT; tile += stride) {
        asm volatile("s_waitcnt vmcnt(0)" ::: "memory");
        __builtin_amdgcn_sched_barrier(0);
        __builtin_amdgcn_s_barrier();
        asm volatile("" ::: "memory");
        int nx = tile + stride;
        if (nx < nT) stage(nx, sel ^ 1);
        __builtin_amdgcn_sched_barrier(0);

        f32x4 acc[2][2];
#pragma unroll
        for (int ct = 0; ct < 2; ++ct)
#pragma unroll
            for (int rt = 0; rt < 2; ++rt) acc[ct][rt] = (f32x4){0.f, 0.f, 0.f, 0.f};

        const short* xs = sX[sel];
#pragma unroll
        for (int ks = 0; ks < 16; ++ks) {
            bf16x8 hf[2];
#pragma unroll
            for (int rt = 0; rt < 2; ++rt) {
                int row = 16 * rt + lrow;
                hf[rt] = *(const bf16x8*)&xs[row * 512 + (((4 * ks + kch) ^ (row & 7)) << 3)];
            }
#pragma unroll
            for (int ct = 0; ct < 2; ++ct)
#pragma unroll
                for (int rt = 0; rt < 2; ++rt)
                    acc[ct][rt] = __builtin_amdgcn_mfma_f32_16x16x32_bf16(w2r[ks][ct], hf[rt], acc[ct][rt], 0, 0, 0);
        }

        int gr0 = tile * 32;
#pragma unroll
        for (int ct = 0; ct < 2; ++ct) {
#pragma unroll
            for (int rt = 0; rt < 2; ++rt) {
                int gr = gr0 + 16 * rt + lrow;
                if (gr < M) {
                    bf16x4 pk;
                    pk[0] = f2bf((acc[ct][rt][0] + bb[ct].x) * scale);
                    pk[1] = f2bf((acc[ct][rt][1] + bb[ct].y) * scale);
                    pk[2] = f2bf((acc[ct][rt][2] + bb[ct].z) * scale);
                    pk[3] = f2bf((acc[ct][rt][3] + bb[ct].w) * scale);
                    *(bf16x4*)(Y8 + ((size_t)wid * M + gr) * 32 + 16 * ct + 4 * kch) = pk;
                }
            }
        }
        sel ^= 1;
    }
}

// ---------------- logits + softmax: 4-lane group per (f,js); LDS-staged coalesced writes ----------------
__global__ __launch_bounds__(256, 2) void logits8_kernel(
    const short* __restrict__ q8, const short* __restrict__ k8,
    const int* __restrict__ rbev, const int* __restrict__ starts,
    const int* __restrict__ lengths, int rn,
    float* __restrict__ Wsm, short* __restrict__ Wg8)
{
    __shared__ float Lex[4][2][40];
    const int h = blockIdx.x & 7;
    const int fb = blockIdx.x >> 3;
    const int t = threadIdx.x;
    const int w = t >> 6;
    const int lane = t & 63;
    const int fsub = lane >> 5;       // 0..1
    const int js = (lane >> 2) & 7;   // 0..7
    const int c = lane & 3;           // chunk 0..3
    const int f = fb * 8 + w * 2 + fsub;
    const int st = starts[f], len = lengths[f];
    const int ntt = (len + 7) >> 3;   // live slots

    bf16x8 kv = *(const bf16x8*)(k8 + ((size_t)h * KLEN + f) * 32 + c * 8);
    const short* qbase = q8 + (size_t)h * TGT * 32;

    int bidx[5];
#pragma unroll
    for (int tt = 0; tt < 5; ++tt) {
        int j = js + 8 * tt;
        bidx[tt] = (j < len) ? rbev[st + j] : 0;
    }
    bf16x8 qv[5];
#pragma unroll
    for (int tt = 0; tt < 5; ++tt)
        qv[tt] = *(const bf16x8*)(qbase + (size_t)bidx[tt] * 32 + c * 8);

    float lg[5];
#pragma unroll
    for (int tt = 0; tt < 5; ++tt) {
        if (tt < ntt) {
            float s = dot8(qv[tt], kv, 0.f);
            s += __shfl_xor(s, 1);
            s += __shfl_xor(s, 2);
            lg[tt] = (js + 8 * tt < len) ? s : -3.0e38f;
        } else {
            lg[tt] = -3.0e38f;
        }
    }

    float m = fmaxf(fmaxf(fmaxf(lg[0], lg[1]), fmaxf(lg[2], lg[3])), lg[4]);
    m = fmaxf(m, __shfl_xor(m, 4));
    m = fmaxf(m, __shfl_xor(m, 8));
    m = fmaxf(m, __shfl_xor(m, 16));
    float ex[5];
    float sum = 0.f;
#pragma unroll
    for (int tt = 0; tt < 5; ++tt) {
        int j = js + 8 * tt;
        float e = (j < len) ? __expf(lg[tt] - m) : 0.f;
        ex[tt] = e;
        sum += e;
    }
    sum += __shfl_xor(sum, 4);
    sum += __shfl_xor(sum, 8);
    sum += __shfl_xor(sum, 16);
    float inv = 1.f / sum;

    // stage normalized weights into LDS (c==0 lanes), then coalesced global writes
    if (c == 0) {
#pragma unroll
        for (int tt = 0; tt < 5; ++tt)
            Lex[w][fsub][js + 8 * tt] = ex[tt] * inv;
    }
    asm volatile("" ::: "memory");   // wave-lockstep LDS ordering

    const int l = lane & 31;
    float* wrow = Wsm + ((size_t)f * HEADS + h) * rn;
    short* grow = Wg8 + ((size_t)h * KLEN + f) * rn;
    const float* lex = &Lex[w][fsub][0];

    // Wsm: float4 per lane (rn/4 lanes), scalar tail
    int nf4 = rn >> 2;
    if (l < nf4) *(float4*)(wrow + l * 4) = *(const float4*)(lex + l * 4);
    int tail4 = rn & 3;
    if (tail4 && l < tail4) wrow[nf4 * 4 + l] = lex[nf4 * 4 + l];

    // Wg8: 8 bf16 per lane (rn/8 lanes), scalar tail
    int ng8 = rn >> 3;
    if (l < ng8) {
        bf16x8 pk;
#pragma unroll
        for (int e = 0; e < 8; ++e) pk[e] = f2bf(lex[l * 8 + e]);
        *(bf16x8*)(grow + l * 8) = pk;
    }
    int tail8 = rn & 7;
    if (tail8 && l < tail8) grow[ng8 * 8 + l] = f2bf(lex[ng8 * 8 + l]);
}

// ---------------- block-scan: coalesced int4 loads, 8 elems/thread, 4 chunks ----------------
__global__ __launch_bounds__(1024) void scan_kernel(
    const int* __restrict__ count, int n,
    int* __restrict__ offs, int* __restrict__ cursor)
{
    __shared__ int wsum[16];
    __shared__ int carry_s;
    const int t = threadIdx.x;
    const int lane = t & 63, wid = t >> 6;
    if (t == 0) carry_s = 0;
    __syncthreads();

    for (int base = 0; base < n; base += 8192) {
        int idx0 = base + t * 8;
        int v[8];
        if (idx0 + 8 <= n) {
            int4 a = *(const int4*)(count + idx0);
            int4 b = *(const int4*)(count + idx0 + 4);
            v[0] = a.x; v[1] = a.y; v[2] = a.z; v[3] = a.w;
            v[4] = b.x; v[5] = b.y; v[6] = b.z; v[7] = b.w;
        } else {
#pragma unroll
            for (int i = 0; i < 8; ++i) v[i] = (idx0 + i < n) ? count[idx0 + i] : 0;
        }
        int loc[8];
        int s = 0;
#pragma unroll
        for (int i = 0; i < 8; ++i) { loc[i] = s; s += v[i]; }
        int incl = wave_incl_scan(s);
        if (lane == 63) wsum[wid] = incl;
        __syncthreads();
        if (wid == 0) {
            int x = (lane < 16) ? wsum[lane] : 0;
            int xi = wave_incl_scan(x);
            if (lane < 16) wsum[lane] = xi;
        }
        __syncthreads();
        int waveoff = (wid > 0) ? wsum[wid - 1] : 0;
        int carry = carry_s;
        int excl = carry + waveoff + incl - s;
        int o[8];
#pragma unroll
        for (int i = 0; i < 8; ++i) o[i] = excl + loc[i];
        if (idx0 + 8 <= n) {
            *(int4*)(offs + idx0)     = make_int4(o[0], o[1], o[2], o[3]);
            *(int4*)(offs + idx0 + 4) = make_int4(o[4], o[5], o[6], o[7]);
            *(int4*)(cursor + idx0)     = make_int4(o[0], o[1], o[2], o[3]);
            *(int4*)(cursor + idx0 + 4) = make_int4(o[4], o[5], o[6], o[7]);
        } else {
#pragma unroll
            for (int i = 0; i < 8; ++i)
                if (idx0 + i < n) { offs[idx0 + i] = o[i]; cursor[idx0 + i] = o[i]; }
        }
        __syncthreads();
        if (t == 1023) carry_s = carry + waveoff + incl;
        __syncthreads();
    }
    if (t == 0) offs[n] = carry_s;
}

// ---------------- permutation fill: pack (f,j) ----------------
__global__ __launch_bounds__(256) void perm_kernel(
    const int* __restrict__ rbev, const int* __restrict__ rfeat,
    const int* __restrict__ starts, int N,
    int* __restrict__ cursor, int* __restrict__ perm)
{
    int n = blockIdx.x * 256 + threadIdx.x;
    if (n < N) {
        int b = rbev[n];
        int f = rfeat[n];
        int j = n - starts[f];
        int pos = atomicAdd(&cursor[b], 1);
        perm[pos] = (f << 6) | j;
    }
}

// ---------------- gather, head-split: 4-thread group per (row,h), explicit ILP ----------------
__global__ __launch_bounds__(256, 2) void gather8_kernel(
    const short* __restrict__ v8, const short* __restrict__ Wg8,
    const int* __restrict__ perm, const int* __restrict__ offs, int rn,
    float* __restrict__ out)
{
    const int h = blockIdx.x & 7;
    const int rb = blockIdx.x >> 3;
    const int t = threadIdx.x;
    const int r = rb * 64 + (t >> 2);
    if (r >= TGT) return;
    const int c = t & 3;
    const int lane = t & 63;
    const int gl = lane & ~3;           // group's base lane
    const short* vbase = v8 + (size_t)h * KLEN * 32 + c * 8;
    const short* wbase = Wg8 + (size_t)h * KLEN * rn;
    const int beg = offs[r], end = offs[r + 1];
    const int cnt = end - beg;
    float acc[8];
#pragma unroll
    for (int e = 0; e < 8; ++e) acc[e] = 0.f;

    for (int base = 0; base < cnt; base += 8) {
        int pk0 = (base + c < cnt) ? perm[beg + base + c] : 0;
        int pk1 = (base + 4 + c < cnt) ? perm[beg + base + 4 + c] : 0;
        short ws[8];
        bf16x8 vv[8];
#pragma unroll
        for (int u = 0; u < 8; ++u) {
            int pku = __shfl(u < 4 ? pk0 : pk1, gl + (u & 3));
            int fo = pku >> 6, j = pku & 63;
            ws[u] = wbase[(size_t)fo * rn + j];
            vv[u] = *(const bf16x8*)(vbase + (size_t)fo * 32);
        }
#pragma unroll
        for (int u = 0; u < 8; ++u) {
            float w = (base + u < cnt) ? bf2f(ws[u]) : 0.f;
#pragma unroll
            for (int e = 0; e < 8; ++e) acc[e] += w * bf2f(vv[u][e]);
        }
    }
    float* o = out + (size_t)r * EMBED + h * 32 + c * 8;
    *(float4*)(o)     = make_float4(acc[0], acc[1], acc[2], acc[3]);
    *(float4*)(o + 4) = make_float4(acc[4], acc[5], acc[6], acc[7]);
}

// ---------------- layernorm in place: one wave per row ----------------
__global__ __launch_bounds__(256) void ln_kernel(
    float* __restrict__ out, const float* __restrict__ g, const float* __restrict__ b)
{
    int row = blockIdx.x * 4 + (threadIdx.x >> 6);
    if (row >= TGT) return;
    int lane = threadIdx.x & 63;
    float4 x = *(float4*)(out + (size_t)row * EMBED + lane * 4);
    float mu = wave_sum(x.x + x.y + x.z + x.w) * (1.f / EMBED);
    float dx = x.x - mu, dy = x.y - mu, dz = x.z - mu, dw = x.w - mu;
    float var = wave_sum(dx * dx + dy * dy + dz * dz + dw * dw) * (1.f / EMBED);
    float rs = rsqrtf(var + LN_EPS);
    float4 gg = *(const float4*)(g + lane * 4);
    float4 bb = *(const float4*)(b + lane * 4);
    float4 y;
    y.x = dx * rs * gg.x + bb.x;
    y.y = dy * rs * gg.y + bb.y;
    y.z = dz * rs * gg.z + bb.z;
    y.w = dw * rs * gg.w + bb.w;
    *(float4*)(out + (size_t)row * EMBED + lane * 4) = y;
}

extern "C" void kernel_launch(void* const* d_in, const int* in_sizes, int n_in,
                              void* d_out, int out_size, void* d_ws, size_t ws_size,
                              hipStream_t stream) {
    const float* query  = (const float*)d_in[0];
    const float* key_in = (const float*)d_in[1];
    const float* value  = (const float*)d_in[2];
    const int* rfeat    = (const int*)d_in[3];
    const int* rbev     = (const int*)d_in[4];
    const int* starts   = (const int*)d_in[5];
    const int* lengths  = (const int*)d_in[6];
    const float* wq1 = (const float*)d_in[7];
    const float* bq1 = (const float*)d_in[8];
    const float* wq2 = (const float*)d_in[9];
    const float* bq2 = (const float*)d_in[10];
    const float* wk1 = (const float*)d_in[11];
    const float* bk1 = (const float*)d_in[12];
    const float* wk2 = (const float*)d_in[13];
    const float* bk2 = (const float*)d_in[14];
    const float* ln_g = (const float*)d_in[15];
    const float* ln_b = (const float*)d_in[16];

    const int N = in_sizes[3];
    const int rn = (out_size - TGT * EMBED) / (KLEN * HEADS); // ref_num

    float* outp = (float*)d_out;
    float* Wsm  = outp + (size_t)TGT * EMBED;

    // workspace layout
    short* Hg   = (short*)d_ws;                          // HROWS*512 bf16
    short* q8   = Hg + (size_t)HROWS * 512;              // 8*TGT*32 bf16
    short* k8   = q8 + (size_t)TGT * EMBED;              // 8*KLEN*32 bf16
    short* v8   = k8 + (size_t)KLEN * EMBED;             // 8*KLEN*32 bf16
    short* Wt   = v8 + (size_t)KLEN * EMBED;             // 4*131072 bf16
    short* Wg8  = Wt + 4 * 131072;                       // 8*KLEN*rn bf16
    int* count  = (int*)(Wg8 + (size_t)HEADS * KLEN * rn);
    int* offs   = count + TGT;                           // TGT+1
    int* cursor = offs + TGT + 1;                        // TGT
    int* perm   = cursor + TGT;                          // N

    const float scaling = 0.1767766952966369f; // 32^-0.5
    const int nQblocks = 168;

    hipMemsetAsync(count, 0, TGT * sizeof(int), stream);

    int hist_blocks = (N + 255) / 256;
    prep_kernel<<<4160 + hist_blocks, 256, 0, stream>>>(
        value, v8, wq1, wq2, wk1, wk2, Wt, rbev, N, count);

    mlpA_kernel<<<256, 512, 0, stream>>>(query, key_in, Wt, bq1, bk1, Hg, nQblocks);
    mlpB_kernel<<<256, 512, 0, stream>>>(Hg, Wt, bq2, bk2, q8, k8, scaling, nQblocks);

    scan_kernel<<<1, 1024, 0, stream>>>(count, TGT, offs, cursor);
    perm_kernel<<<(N + 255) / 256, 256, 0, stream>>>(rbev, rfeat, starts, N, cursor, perm);

    logits8_kernel<<<8 * (KLEN / 8), 256, 0, stream>>>(
        q8, k8, rbev, starts, lengths, rn, Wsm, Wg8);

    gather8_kernel<<<8 * ((TGT + 63) / 64), 256, 0, stream>>>(
        v8, Wg8, perm, offs, rn, outp);
    ln_kernel<<<(TGT + 3) / 4, 256, 0, stream>>>(outp, ln_g, ln_b);
}

// Round 19
// 198.462 us; speedup vs baseline: 1.0341x; 1.0287x over previous
//
#include <hip/hip_runtime.h>
#include <math.h>

#define TGT 32400
#define KLEN 16896
#define EMBED 256
#define HID 512
#define HEADS 8
#define LN_EPS 1e-5f

#define NQT 1013              // ceil(32400/32) layer tiles for Q
#define NKT 528               // 16896/32
#define HROWS ((NQT + NKT) * 32)

typedef __attribute__((ext_vector_type(8))) short bf16x8;
typedef __attribute__((ext_vector_type(4))) short bf16x4;
typedef __attribute__((ext_vector_type(4))) float f32x4;
typedef __attribute__((ext_vector_type(2))) __bf16 bfv2;

__device__ inline short f2bf(float f) {
    union { float f; unsigned u; } v; v.f = f;
    unsigned r = v.u + 0x7FFF + ((v.u >> 16) & 1);
    return (short)(r >> 16);
}
__device__ inline float bf2f(short s) {
    union { unsigned u; float f; } v;
    v.u = ((unsigned)(unsigned short)s) << 16;
    return v.f;
}
__device__ inline void gload_lds16(const short* g, short* l) {
    __builtin_amdgcn_global_load_lds(
        (const __attribute__((address_space(1))) void*)g,
        (__attribute__((address_space(3))) void*)l,
        16, 0, 0);
}

// 8-elem bf16 dot with f32 accumulate; hw dot2 when available
__device__ inline float dot8(bf16x8 q, bf16x8 k, float s) {
#if __has_builtin(__builtin_amdgcn_fdot2_f32_bf16)
    union { bf16x8 v; bfv2 p[4]; } qu, ku;
    qu.v = q; ku.v = k;
#pragma unroll
    for (int p = 0; p < 4; ++p)
        s = __builtin_amdgcn_fdot2_f32_bf16(qu.p[p], ku.p[p], s, false);
#else
#pragma unroll
    for (int e = 0; e < 8; ++e) s += bf2f(q[e]) * bf2f(k[e]);
#endif
    return s;
}

// ---------------- wave helpers (wave64) ----------------
__device__ inline float wave_sum(float v) {
#pragma unroll
    for (int o = 32; o; o >>= 1) v += __shfl_xor(v, o);
    return v;
}
__device__ inline int wave_incl_scan(int v) {
    int lane = threadIdx.x & 63;
#pragma unroll
    for (int o = 1; o < 64; o <<= 1) {
        int x = __shfl_up(v, o);
        if (lane >= o) v += x;
    }
    return v;
}

// ---------------- prep: value->v8 (head-major bf16), weight transpose, histogram ----------------
__global__ __launch_bounds__(256) void prep_kernel(
    const float* __restrict__ value, short* __restrict__ v8,
    const float* __restrict__ wq1, const float* __restrict__ wq2,
    const float* __restrict__ wk1, const float* __restrict__ wk2,
    short* __restrict__ Wt,
    const int* __restrict__ rbev, int N, int* __restrict__ count)
{
    int bid = blockIdx.x;
    if (bid < 2112) {
        int idx = bid * 256 + threadIdx.x;       // chunk of 8 floats
        int f = idx >> 5;                        // row
        int ch = idx & 31;                       // chunk in row
        const float4* s4 = (const float4*)(value + (size_t)f * 256 + ch * 8);
        float4 a = s4[0], b = s4[1];
        bf16x8 pk;
        pk[0] = f2bf(a.x); pk[1] = f2bf(a.y); pk[2] = f2bf(a.z); pk[3] = f2bf(a.w);
        pk[4] = f2bf(b.x); pk[5] = f2bf(b.y); pk[6] = f2bf(b.z); pk[7] = f2bf(b.w);
        int head = ch >> 2;
        int within = (ch & 3) * 8;
        *(bf16x8*)(v8 + ((size_t)head * KLEN + f) * 32 + within) = pk;
    } else if (bid < 4160) {
        int i = (bid - 2112) * 256 + threadIdx.x;
        int m = i >> 17;
        int r17 = i & 131071;
        int logC = (m & 1) ? 8 : 9;
        int C = 1 << logC;
        int c = r17 & (C - 1);
        int r = r17 >> logC;
        int R = 131072 >> logC;
        const float* W = (m == 0) ? wq1 : (m == 1) ? wq2 : (m == 2) ? wk1 : wk2;
        Wt[(size_t)m * 131072 + (size_t)c * R + r] = f2bf(W[r17]);
    } else {
        int n = (bid - 4160) * 256 + threadIdx.x;
        if (n < N) atomicAdd(&count[rbev[n]], 1);
    }
}

// ---------------- MLP layer 1: persistent, W1-in-registers ----------------
#define XPAD 264
__global__ __launch_bounds__(512, 2) void mlpA_kernel(
    const float* __restrict__ Xq, const float* __restrict__ Xk,
    const short* __restrict__ Wt,
    const float* __restrict__ bq1, const float* __restrict__ bk1,
    short* __restrict__ Hg, int nQblocks)
{
    __shared__ short sX[2][32 * XPAD];

    const int t = threadIdx.x;
    const int wid = t >> 6, lane = t & 63;
    const int lrow = lane & 15, kch = lane >> 4;

    const bool isQ = (int)blockIdx.x < nQblocks;
    const int bid = isQ ? blockIdx.x : blockIdx.x - nQblocks;
    const int stride = isQ ? nQblocks : (gridDim.x - nQblocks);
    const int nT = isQ ? NQT : NKT;
    const int M = isQ ? TGT : KLEN;
    const float* X = isQ ? Xq : Xk;
    const short* W1t = Wt + (size_t)(isQ ? 0 : 2) * 131072;
    const float* b1 = isQ ? bq1 : bk1;
    const int hbase = isQ ? 0 : NQT * 32;

    const int colBase = 64 * wid + lrow;

    bf16x8 w1r[8][4];
#pragma unroll
    for (int ks = 0; ks < 8; ++ks)
#pragma unroll
        for (int j = 0; j < 4; ++j)
            w1r[ks][j] = *(const bf16x8*)(W1t + (size_t)(colBase + 16 * j) * 256 + 32 * ks + 8 * kch);
    float4 bb[4];
#pragma unroll
    for (int j = 0; j < 4; ++j)
        bb[j] = *(const float4*)(b1 + 64 * wid + 16 * j + 4 * kch);

    const int srow = t >> 4, sp = t & 15;

    float4 r0[4], r1[4];
    int tile = bid;
    if (tile < nT) {
        int gr = tile * 32 + srow; if (gr > M - 1) gr = M - 1;
        const float* base = X + (size_t)gr * 256;
#pragma unroll
        for (int i = 0; i < 4; ++i) r0[i] = *(const float4*)(base + (sp + 16 * i) * 4);
    }
    int sel = 0;

    for (; tile < nT; tile += stride) {
#pragma unroll
        for (int i = 0; i < 4; ++i) {
            int c = sp + 16 * i;
            bf16x4 pk;
            pk[0] = f2bf(r0[i].x); pk[1] = f2bf(r0[i].y);
            pk[2] = f2bf(r0[i].z); pk[3] = f2bf(r0[i].w);
            *(bf16x4*)&sX[sel][srow * XPAD + c * 4] = pk;
        }
        int nx = tile + stride;
        if (nx < nT) {
            int gr = nx * 32 + srow; if (gr > M - 1) gr = M - 1;
            const float* base = X + (size_t)gr * 256;
#pragma unroll
            for (int i = 0; i < 4; ++i) r1[i] = *(const float4*)(base + (sp + 16 * i) * 4);
        }
        asm volatile("s_waitcnt lgkmcnt(0)" ::: "memory");
        __builtin_amdgcn_sched_barrier(0);
        __builtin_amdgcn_s_barrier();
        asm volatile("" ::: "memory");

        f32x4 acc[2][4];
#pragma unroll
        for (int rt = 0; rt < 2; ++rt)
#pragma unroll
            for (int j = 0; j < 4; ++j) acc[rt][j] = (f32x4){0.f, 0.f, 0.f, 0.f};

        const short* xs = sX[sel];
#pragma unroll
        for (int ks = 0; ks < 8; ++ks) {
            bf16x8 af[2];
#pragma unroll
            for (int rt = 0; rt < 2; ++rt)
                af[rt] = *(const bf16x8*)&xs[(16 * rt + lrow) * XPAD + 32 * ks + 8 * kch];
#pragma unroll
            for (int j = 0; j < 4; ++j)
#pragma unroll
                for (int rt = 0; rt < 2; ++rt)
                    acc[rt][j] = __builtin_amdgcn_mfma_f32_16x16x32_bf16(w1r[ks][j], af[rt], acc[rt][j], 0, 0, 0);
        }

        int hr0 = hbase + tile * 32;
#pragma unroll
        for (int j = 0; j < 4; ++j) {
#pragma unroll
            for (int rt = 0; rt < 2; ++rt) {
                bf16x4 pk;
                pk[0] = f2bf(fmaxf(acc[rt][j][0] + bb[j].x, 0.f));
                pk[1] = f2bf(fmaxf(acc[rt][j][1] + bb[j].y, 0.f));
                pk[2] = f2bf(fmaxf(acc[rt][j][2] + bb[j].z, 0.f));
                pk[3] = f2bf(fmaxf(acc[rt][j][3] + bb[j].w, 0.f));
                *(bf16x4*)(Hg + (size_t)(hr0 + 16 * rt + lrow) * 512 + 64 * wid + 16 * j + 4 * kch) = pk;
            }
        }
#pragma unroll
        for (int i = 0; i < 4; ++i) r0[i] = r1[i];
        sel ^= 1;
    }
}

// ---------------- MLP layer 2: persistent, W2-in-registers, writes head-major q8/k8 ----------------
__global__ __launch_bounds__(512, 2) void mlpB_kernel(
    const short* __restrict__ Hg, const short* __restrict__ Wt,
    const float* __restrict__ bq2, const float* __restrict__ bk2,
    short* __restrict__ q8, short* __restrict__ k8,
    float scaleQ, int nQblocks)
{
    __shared__ short sX[2][32 * 512];

    const int t = threadIdx.x;
    const int wid = t >> 6, lane = t & 63;
    const int lrow = lane & 15, kch = lane >> 4;

    const bool isQ = (int)blockIdx.x < nQblocks;
    const int bid = isQ ? blockIdx.x : blockIdx.x - nQblocks;
    const int stride = isQ ? nQblocks : (gridDim.x - nQblocks);
    const int nT = isQ ? NQT : NKT;
    const int M = isQ ? TGT : KLEN;
    const short* W2t = Wt + (size_t)(isQ ? 1 : 3) * 131072;
    const float* b2 = isQ ? bq2 : bk2;
    short* Y8 = isQ ? q8 : k8;
    const int hbase = isQ ? 0 : NQT * 32;
    const float scale = isQ ? scaleQ : 1.0f;

    const int colBase = 32 * wid + lrow;

    bf16x8 w2r[16][2];
#pragma unroll
    for (int ks = 0; ks < 16; ++ks)
#pragma unroll
        for (int ct = 0; ct < 2; ++ct)
            w2r[ks][ct] = *(const bf16x8*)(W2t + (size_t)(colBase + 16 * ct) * 512 + 32 * ks + 8 * kch);
    float4 bb[2];
#pragma unroll
    for (int ct = 0; ct < 2; ++ct)
        bb[ct] = *(const float4*)(b2 + 32 * wid + 16 * ct + 4 * kch);

    auto stage = [&](int tt, int s) {
#pragma unroll
        for (int i = 0; i < 4; ++i) {
            int baseslot = i * 512 + wid * 64;
            int slot = baseslot + lane;
            int r = slot >> 6;
            int d = slot & 63;
            int cs = d ^ (r & 7);
            gload_lds16(Hg + (size_t)(hbase + tt * 32 + r) * 512 + cs * 8,
                        &sX[s][baseslot * 8]);
        }
    };

    int tile = bid;
    int sel = 0;
    if (tile < nT) stage(tile, 0);

    for (; tile < nT; tile += stride) {
        asm volatile("s_waitcnt vmcnt(0)" ::: "memory");
        __builtin_amdgcn_sched_barrier(0);
        __builtin_amdgcn_s_barrier();
        asm volatile("" ::: "memory");
        int nx = tile + stride;
        if (nx < nT) stage(nx, sel ^ 1);
        __builtin_amdgcn_sched_barrier(0);

        f32x4 acc[2][2];
#pragma unroll
        for (int ct = 0; ct < 2; ++ct)
#pragma unroll
            for (int rt = 0; rt < 2; ++rt) acc[ct][rt] = (f32x4){0.f, 0.f, 0.f, 0.f};

        const short* xs = sX[sel];
#pragma unroll
        for (int ks = 0; ks < 16; ++ks) {
            bf16x8 hf[2];
#pragma unroll
            for (int rt = 0; rt < 2; ++rt) {
                int row = 16 * rt + lrow;
                hf[rt] = *(const bf16x8*)&xs[row * 512 + (((4 * ks + kch) ^ (row & 7)) << 3)];
            }
#pragma unroll
            for (int ct = 0; ct < 2; ++ct)
#pragma unroll
                for (int rt = 0; rt < 2; ++rt)
                    acc[ct][rt] = __builtin_amdgcn_mfma_f32_16x16x32_bf16(w2r[ks][ct], hf[rt], acc[ct][rt], 0, 0, 0);
        }

        int gr0 = tile * 32;
#pragma unroll
        for (int ct = 0; ct < 2; ++ct) {
#pragma unroll
            for (int rt = 0; rt < 2; ++rt) {
                int gr = gr0 + 16 * rt + lrow;
                if (gr < M) {
                    bf16x4 pk;
                    pk[0] = f2bf((acc[ct][rt][0] + bb[ct].x) * scale);
                    pk[1] = f2bf((acc[ct][rt][1] + bb[ct].y) * scale);
                    pk[2] = f2bf((acc[ct][rt][2] + bb[ct].z) * scale);
                    pk[3] = f2bf((acc[ct][rt][3] + bb[ct].w) * scale);
                    *(bf16x4*)(Y8 + ((size_t)wid * M + gr) * 32 + 16 * ct + 4 * kch) = pk;
                }
            }
        }
        sel ^= 1;
    }
}

// ---------------- logits + softmax: 4-lane group per (f,js); pinned load phase ----------------
__global__ __launch_bounds__(256, 2) void logits8_kernel(
    const short* __restrict__ q8, const short* __restrict__ k8,
    const int* __restrict__ rbev, const int* __restrict__ starts,
    const int* __restrict__ lengths, int rn,
    float* __restrict__ Wsm, short* __restrict__ Wg8)
{
    __shared__ float Lex[4][2][40];
    const int h = blockIdx.x & 7;
    const int fb = blockIdx.x >> 3;
    const int t = threadIdx.x;
    const int w = t >> 6;
    const int lane = t & 63;
    const int fsub = lane >> 5;       // 0..1
    const int js = (lane >> 2) & 7;   // 0..7
    const int c = lane & 3;           // chunk 0..3
    const int f = fb * 8 + w * 2 + fsub;
    const int st = starts[f], len = lengths[f];

    bf16x8 kv = *(const bf16x8*)(k8 + ((size_t)h * KLEN + f) * 32 + c * 8);
    const short* qbase = q8 + (size_t)h * TGT * 32;

    int bidx[5];
#pragma unroll
    for (int tt = 0; tt < 5; ++tt) {
        int j = js + 8 * tt;
        bidx[tt] = (j < len) ? rbev[st + j] : 0;
    }
    // load phase: all 5 q-chunks; sched_barrier pins them before any use
    bf16x8 qv[5];
#pragma unroll
    for (int tt = 0; tt < 5; ++tt)
        qv[tt] = *(const bf16x8*)(qbase + (size_t)bidx[tt] * 32 + c * 8);
    __builtin_amdgcn_sched_barrier(0);

    float lg[5];
#pragma unroll
    for (int tt = 0; tt < 5; ++tt) {
        float s = dot8(qv[tt], kv, 0.f);
        s += __shfl_xor(s, 1);
        s += __shfl_xor(s, 2);
        lg[tt] = (js + 8 * tt < len) ? s : -3.0e38f;
    }

    float m = fmaxf(fmaxf(fmaxf(lg[0], lg[1]), fmaxf(lg[2], lg[3])), lg[4]);
    m = fmaxf(m, __shfl_xor(m, 4));
    m = fmaxf(m, __shfl_xor(m, 8));
    m = fmaxf(m, __shfl_xor(m, 16));
    float ex[5];
    float sum = 0.f;
#pragma unroll
    for (int tt = 0; tt < 5; ++tt) {
        int j = js + 8 * tt;
        float e = (j < len) ? __expf(lg[tt] - m) : 0.f;
        ex[tt] = e;
        sum += e;
    }
    sum += __shfl_xor(sum, 4);
    sum += __shfl_xor(sum, 8);
    sum += __shfl_xor(sum, 16);
    float inv = 1.f / sum;

    if (c == 0) {
#pragma unroll
        for (int tt = 0; tt < 5; ++tt)
            Lex[w][fsub][js + 8 * tt] = ex[tt] * inv;
    }
    asm volatile("" ::: "memory");

    const int l = lane & 31;
    float* wrow = Wsm + ((size_t)f * HEADS + h) * rn;
    short* grow = Wg8 + ((size_t)h * KLEN + f) * rn;
    const float* lex = &Lex[w][fsub][0];

    int nf4 = rn >> 2;
    if (l < nf4) *(float4*)(wrow + l * 4) = *(const float4*)(lex + l * 4);
    int tail4 = rn & 3;
    if (tail4 && l < tail4) wrow[nf4 * 4 + l] = lex[nf4 * 4 + l];

    int ng8 = rn >> 3;
    if (l < ng8) {
        bf16x8 pk;
#pragma unroll
        for (int e = 0; e < 8; ++e) pk[e] = f2bf(lex[l * 8 + e]);
        *(bf16x8*)(grow + l * 8) = pk;
    }
    int tail8 = rn & 7;
    if (tail8 && l < tail8) grow[ng8 * 8 + l] = f2bf(lex[ng8 * 8 + l]);
}

// ---------------- block-scan: coalesced int4 loads, 8 elems/thread, 4 chunks ----------------
__global__ __launch_bounds__(1024) void scan_kernel(
    const int* __restrict__ count, int n,
    int* __restrict__ offs, int* __restrict__ cursor)
{
    __shared__ int wsum[16];
    __shared__ int carry_s;
    const int t = threadIdx.x;
    const int lane = t & 63, wid = t >> 6;
    if (t == 0) carry_s = 0;
    __syncthreads();

    for (int base = 0; base < n; base += 8192) {
        int idx0 = base + t * 8;
        int v[8];
        if (idx0 + 8 <= n) {
            int4 a = *(const int4*)(count + idx0);
            int4 b = *(const int4*)(count + idx0 + 4);
            v[0] = a.x; v[1] = a.y; v[2] = a.z; v[3] = a.w;
            v[4] = b.x; v[5] = b.y; v[6] = b.z; v[7] = b.w;
        } else {
#pragma unroll
            for (int i = 0; i < 8; ++i) v[i] = (idx0 + i < n) ? count[idx0 + i] : 0;
        }
        int loc[8];
        int s = 0;
#pragma unroll
        for (int i = 0; i < 8; ++i) { loc[i] = s; s += v[i]; }
        int incl = wave_incl_scan(s);
        if (lane == 63) wsum[wid] = incl;
        __syncthreads();
        if (wid == 0) {
            int x = (lane < 16) ? wsum[lane] : 0;
            int xi = wave_incl_scan(x);
            if (lane < 16) wsum[lane] = xi;
        }
        __syncthreads();
        int waveoff = (wid > 0) ? wsum[wid - 1] : 0;
        int carry = carry_s;
        int excl = carry + waveoff + incl - s;
        int o[8];
#pragma unroll
        for (int i = 0; i < 8; ++i) o[i] = excl + loc[i];
        if (idx0 + 8 <= n) {
            *(int4*)(offs + idx0)     = make_int4(o[0], o[1], o[2], o[3]);
            *(int4*)(offs + idx0 + 4) = make_int4(o[4], o[5], o[6], o[7]);
            *(int4*)(cursor + idx0)     = make_int4(o[0], o[1], o[2], o[3]);
            *(int4*)(cursor + idx0 + 4) = make_int4(o[4], o[5], o[6], o[7]);
        } else {
#pragma unroll
            for (int i = 0; i < 8; ++i)
                if (idx0 + i < n) { offs[idx0 + i] = o[i]; cursor[idx0 + i] = o[i]; }
        }
        __syncthreads();
        if (t == 1023) carry_s = carry + waveoff + incl;
        __syncthreads();
    }
    if (t == 0) offs[n] = carry_s;
}

// ---------------- permutation fill: pack (f,j) ----------------
__global__ __launch_bounds__(256) void perm_kernel(
    const int* __restrict__ rbev, const int* __restrict__ rfeat,
    const int* __restrict__ starts, int N,
    int* __restrict__ cursor, int* __restrict__ perm)
{
    int n = blockIdx.x * 256 + threadIdx.x;
    if (n < N) {
        int b = rbev[n];
        int f = rfeat[n];
        int j = n - starts[f];
        int pos = atomicAdd(&cursor[b], 1);
        perm[pos] = (f << 6) | j;
    }
}

// ---------------- gather, head-split: 4-thread group per (row,h), pinned load phase ----------------
__global__ __launch_bounds__(256, 2) void gather8_kernel(
    const short* __restrict__ v8, const short* __restrict__ Wg8,
    const int* __restrict__ perm, const int* __restrict__ offs, int rn,
    float* __restrict__ out)
{
    const int h = blockIdx.x & 7;
    const int rb = blockIdx.x >> 3;
    const int t = threadIdx.x;
    const int r = rb * 64 + (t >> 2);
    if (r >= TGT) return;
    const int c = t & 3;
    const int lane = t & 63;
    const int gl = lane & ~3;           // group's base lane
    const short* vbase = v8 + (size_t)h * KLEN * 32 + c * 8;
    const short* wbase = Wg8 + (size_t)h * KLEN * rn;
    const int beg = offs[r], end = offs[r + 1];
    const int cnt = end - beg;
    float acc[8];
#pragma unroll
    for (int e = 0; e < 8; ++e) acc[e] = 0.f;

    for (int base = 0; base < cnt; base += 8) {
        int pk0 = (base + c < cnt) ? perm[beg + base + c] : 0;
        int pk1 = (base + 4 + c < cnt) ? perm[beg + base + 4 + c] : 0;
        // load phase: all 16 loads issued; sched_barrier pins them before uses
        short ws[8];
        bf16x8 vv[8];
#pragma unroll
        for (int u = 0; u < 8; ++u) {
            int pku = __shfl(u < 4 ? pk0 : pk1, gl + (u & 3));
            int fo = pku >> 6, j = pku & 63;
            ws[u] = wbase[(size_t)fo * rn + j];
            vv[u] = *(const bf16x8*)(vbase + (size_t)fo * 32);
        }
        __builtin_amdgcn_sched_barrier(0);
#pragma unroll
        for (int u = 0; u < 8; ++u) {
            float w = (base + u < cnt) ? bf2f(ws[u]) : 0.f;
#pragma unroll
            for (int e = 0; e < 8; ++e) acc[e] += w * bf2f(vv[u][e]);
        }
    }
    float* o = out + (size_t)r * EMBED + h * 32 + c * 8;
    *(float4*)(o)     = make_float4(acc[0], acc[1], acc[2], acc[3]);
    *(float4*)(o + 4) = make_float4(acc[4], acc[5], acc[6], acc[7]);
}

// ---------------- layernorm in place: one wave per row ----------------
__global__ __launch_bounds__(256) void ln_kernel(
    float* __restrict__ out, const float* __restrict__ g, const float* __restrict__ b)
{
    int row = blockIdx.x * 4 + (threadIdx.x >> 6);
    if (row >= TGT) return;
    int lane = threadIdx.x & 63;
    float4 x = *(float4*)(out + (size_t)row * EMBED + lane * 4);
    float mu = wave_sum(x.x + x.y + x.z + x.w) * (1.f / EMBED);
    float dx = x.x - mu, dy = x.y - mu, dz = x.z - mu, dw = x.w - mu;
    float var = wave_sum(dx * dx + dy * dy + dz * dz + dw * dw) * (1.f / EMBED);
    float rs = rsqrtf(var + LN_EPS);
    float4 gg = *(const float4*)(g + lane * 4);
    float4 bb = *(const float4*)(b + lane * 4);
    float4 y;
    y.x = dx * rs * gg.x + bb.x;
    y.y = dy * rs * gg.y + bb.y;
    y.z = dz * rs * gg.z + bb.z;
    y.w = dw * rs * gg.w + bb.w;
    *(float4*)(out + (size_t)row * EMBED + lane * 4) = y;
}

extern "C" void kernel_launch(void* const* d_in, const int* in_sizes, int n_in,
                              void* d_out, int out_size, void* d_ws, size_t ws_size,
                              hipStream_t stream) {
    const float* query  = (const float*)d_in[0];
    const float* key_in = (const float*)d_in[1];
    const float* value  = (const float*)d_in[2];
    const int* rfeat    = (const int*)d_in[3];
    const int* rbev     = (const int*)d_in[4];
    const int* starts   = (const int*)d_in[5];
    const int* lengths  = (const int*)d_in[6];
    const float* wq1 = (const float*)d_in[7];
    const float* bq1 = (const float*)d_in[8];
    const float* wq2 = (const float*)d_in[9];
    const float* bq2 = (const float*)d_in[10];
    const float* wk1 = (const float*)d_in[11];
    const float* bk1 = (const float*)d_in[12];
    const float* wk2 = (const float*)d_in[13];
    const float* bk2 = (const float*)d_in[14];
    const float* ln_g = (const float*)d_in[15];
    const float* ln_b = (const float*)d_in[16];

    const int N = in_sizes[3];
    const int rn = (out_size - TGT * EMBED) / (KLEN * HEADS); // ref_num

    float* outp = (float*)d_out;
    float* Wsm  = outp + (size_t)TGT * EMBED;

    // workspace layout
    short* Hg   = (short*)d_ws;                          // HROWS*512 bf16
    short* q8   = Hg + (size_t)HROWS * 512;              // 8*TGT*32 bf16
    short* k8   = q8 + (size_t)TGT * EMBED;              // 8*KLEN*32 bf16
    short* v8   = k8 + (size_t)KLEN * EMBED;             // 8*KLEN*32 bf16
    short* Wt   = v8 + (size_t)KLEN * EMBED;             // 4*131072 bf16
    short* Wg8  = Wt + 4 * 131072;                       // 8*KLEN*rn bf16
    int* count  = (int*)(Wg8 + (size_t)HEADS * KLEN * rn);
    int* offs   = count + TGT;                           // TGT+1
    int* cursor = offs + TGT + 1;                        // TGT
    int* perm   = cursor + TGT;                          // N

    const float scaling = 0.1767766952966369f; // 32^-0.5
    const int nQblocks = 168;

    hipMemsetAsync(count, 0, TGT * sizeof(int), stream);

    int hist_blocks = (N + 255) / 256;
    prep_kernel<<<4160 + hist_blocks, 256, 0, stream>>>(
        value, v8, wq1, wq2, wk1, wk2, Wt, rbev, N, count);

    mlpA_kernel<<<256, 512, 0, stream>>>(query, key_in, Wt, bq1, bk1, Hg, nQblocks);
    mlpB_kernel<<<256, 512, 0, stream>>>(Hg, Wt, bq2, bk2, q8, k8, scaling, nQblocks);

    scan_kernel<<<1, 1024, 0, stream>>>(count, TGT, offs, cursor);
    perm_kernel<<<(N + 255) / 256, 256, 0, stream>>>(rbev, rfeat, starts, N, cursor, perm);

    logits8_kernel<<<8 * (KLEN / 8), 256, 0, stream>>>(
        q8, k8, rbev, starts, lengths, rn, Wsm, Wg8);

    gather8_kernel<<<8 * ((TGT + 63) / 64), 256, 0, stream>>>(
        v8, Wg8, perm, offs, rn, outp);
    ln_kernel<<<(TGT + 3) / 4, 256, 0, stream>>>(outp, ln_g, ln_b);
}